// Round 19
// baseline (221.424 us; speedup 1.0000x reference)
//
#include <hip/hip_runtime.h>
#include <hip/hip_bf16.h>
#include <math.h>

#define N_NODES   100000
#define N_EDGES   1600000
#define IN_FEAT   50
#define HIDDEN    64
#define N_CLASSES 41
#define NC48      48          // padded class width
#define N_TILES   (N_NODES / 16)   // 6250 exactly
#define XW        56          // packed x width (50 real + 6 pad), 112 B rows
#define XQ        7           // quads per x row

// bucketed counting sort (fixed-capacity regions, no pre-histogram)
#define NPB   200                      // nodes per bucket
#define NBUK  (N_NODES / NPB)          // 500 buckets exactly
#define SLOTS 4096                     // fixed region capacity per bucket
#define BEPT  16                       // edges per thread in bucketA
#define BA_BLOCKS ((N_EDGES + 256 * BEPT - 1) / (256 * BEPT))  // 391
#define SCAP  4096                     // sort2 LDS staging (== SLOTS)

#define PACKX_BLOCKS (N_NODES * XW / 256)   // 21875 exactly
#define PW_BLOCKS    28                     // 7168 / 256

typedef __attribute__((ext_vector_type(8))) _Float16 half8;
typedef __attribute__((ext_vector_type(4))) float   float4v;

union f16pk { _Float16 h[2]; unsigned u; };

// index clamp: any value outside [0,N_NODES) becomes 0 (defensive)
__device__ __forceinline__ int clampidx(int i) {
  return ((unsigned)i < (unsigned)N_NODES) ? i : 0;
}

// edge-offset clamp: any value outside [0,N_EDGES] becomes 0 (defensive)
__device__ __forceinline__ int clampoff(int v) {
  return ((unsigned)v <= (unsigned)N_EDGES) ? v : 0;
}

// f16 accumulate; `one` runtime arg prevents fma->fadd unfusing
__device__ __forceinline__ void acc8(float* acc, half8 u, float one) {
#pragma unroll
  for (int t = 0; t < 8; ++t) acc[t] = fmaf((float)u[t], one, acc[t]);
}

// fp8x8 (uint2) -> 8 f32 accumulate via HW v_cvt_pk_f32_fp8 (OCP e4m3)
__device__ __forceinline__ void accf8(float* acc, uint2 u) {
  auto p0 = __builtin_amdgcn_cvt_pk_f32_fp8(u.x, 0);
  auto p1 = __builtin_amdgcn_cvt_pk_f32_fp8(u.x, 1);
  auto p2 = __builtin_amdgcn_cvt_pk_f32_fp8(u.y, 0);
  auto p3 = __builtin_amdgcn_cvt_pk_f32_fp8(u.y, 1);
  acc[0] += p0[0]; acc[1] += p0[1];
  acc[2] += p1[0]; acc[3] += p1[1];
  acc[4] += p2[0]; acc[5] += p2[1];
  acc[6] += p3[0]; acc[7] += p3[1];
}

// ---------------------------------------------------------------------------
// K1 bucketA (R15-proven): fixed bucket regions, no pre-histogram.
// wcur2 zero-init via hipMemsetAsync.
// ---------------------------------------------------------------------------
__global__ __launch_bounds__(256) void bucketA_kernel(
    const int* __restrict__ src, const int* __restrict__ dst,
    int* __restrict__ wcur2, int* __restrict__ pairs) {
  __shared__ int lcnt[NBUK];
  __shared__ int lbase[NBUK];
  int tid = threadIdx.x;
  for (int i = tid; i < NBUK; i += 256) { lcnt[i] = 0; lbase[i] = 0; }
  __syncthreads();

  int base = blockIdx.x * (256 * BEPT);
  int pk[BEPT], w[BEPT], rk[BEPT];
#pragma unroll
  for (int k = 0; k < BEPT; ++k) {
    int e = base + k * 256 + tid;
    rk[k] = -1;
    if (e < N_EDGES) {
      int sv = clampidx(src[e]);
      int d = clampidx(dst[e]);
      w[k] = (unsigned)d / (unsigned)NPB;           // < NBUK by construction
      pk[k] = (sv << 8) | (d - w[k] * NPB);
      rk[k] = atomicAdd(&lcnt[w[k]], 1);
    }
  }
  __syncthreads();
  for (int i = tid; i < NBUK; i += 256)
    if (lcnt[i]) lbase[i] = atomicAdd(&wcur2[i], lcnt[i]);
  __syncthreads();
#pragma unroll
  for (int k = 0; k < BEPT; ++k) {
    if (rk[k] >= 0) {
      unsigned rel = (unsigned)(lbase[w[k]] + rk[k]);
      if (rel < (unsigned)SLOTS) pairs[w[k] * SLOTS + (int)rel] = pk[k];
    }
  }
}

// ---------------------------------------------------------------------------
// K2 sortprep (R18-proven): merged sort2 + prep dispatch.
// ---------------------------------------------------------------------------
__global__ __launch_bounds__(256) void sortprep_kernel(
    const int* __restrict__ pairs, const int* __restrict__ wcur2,
    int* __restrict__ start, int* __restrict__ ssrc,
    const float* __restrict__ x, _Float16* __restrict__ xh,
    const float* __restrict__ W1l, const float* __restrict__ W1r,
    const float* __restrict__ W2l, const float* __restrict__ W2r,
    unsigned* __restrict__ wt1l, unsigned* __restrict__ wt1r,
    unsigned* __restrict__ wt2l, unsigned* __restrict__ wt2r) {
  __shared__ int obuf[SCAP];
  __shared__ int lhist[NPB];
  __shared__ int lcur[NPB];
  __shared__ int lscan[256];
  __shared__ int lohi[2];
  int tid = threadIdx.x;

  if (blockIdx.x >= NBUK) {
    // ---- prep half ----
    int bb = blockIdx.x - NBUK;
    if (bb < PACKX_BLOCKS) {
      int i = bb * 256 + tid;                        // < N*56 exactly
      int node = i / XW, c = i - node * XW;
      xh[i] = (c < IN_FEAT) ? (_Float16)x[node * IN_FEAT + c] : (_Float16)0.f;
      return;
    }
    if (bb == PACKX_BLOCKS && tid == 0) start[N_NODES] = N_EDGES;  // sentinel
    int i = (bb - PACKX_BLOCKS) * 256 + tid;         // [0, 7168)
    f16pk pk;
    if (i < 2048 * 2) {                       // layer-1 weights
      int which = i >> 11, j = i & 2047;
      int n = j >> 5, kp = j & 31;
      const float* W = which ? W1r : W1l;
      int k0 = 2 * kp, k1 = 2 * kp + 1;
      pk.h[0] = (_Float16)((k0 < IN_FEAT) ? W[k0 * HIDDEN + n] : 0.f);
      pk.h[1] = (_Float16)((k1 < IN_FEAT) ? W[k1 * HIDDEN + n] : 0.f);
      (which ? wt1r : wt1l)[j] = pk.u;
    } else if (i < 4096 + 2 * 1536) {         // layer-2 weights
      int j = i - 4096;
      int which = (j >= 1536), jj = which ? j - 1536 : j;
      int n = jj >> 5, kp = jj & 31;
      const float* W = which ? W2r : W2l;
      pk.h[0] = (_Float16)((n < N_CLASSES) ? W[(2 * kp) * N_CLASSES + n] : 0.f);
      pk.h[1] = (_Float16)((n < N_CLASSES) ? W[(2 * kp + 1) * N_CLASSES + n] : 0.f);
      (which ? wt2r : wt2l)[jj] = pk.u;
    }
    return;
  }

  // ---- sort2 half (R15-proven body) ----
  int b = blockIdx.x;
  int nbase = b * NPB;
  {
    int i0 = 2 * tid, i1 = 2 * tid + 1;
    int a0 = (i0 < NBUK) ? min(max(wcur2[i0], 0), SLOTS) : 0;
    int a1 = (i1 < NBUK) ? min(max(wcur2[i1], 0), SLOTS) : 0;
    int s = a0 + a1;
    lscan[tid] = s;
    __syncthreads();
    for (int off = 1; off < 256; off <<= 1) {
      int t = (tid >= off) ? lscan[tid - off] : 0;
      __syncthreads();
      lscan[tid] += t;
      __syncthreads();
    }
    int excl = lscan[tid] - s;
    if (i0 == b) { lohi[0] = excl;      lohi[1] = a0; }
    if (i1 == b) { lohi[0] = excl + a0; lohi[1] = a1; }
  }
  for (int i = tid; i < NPB; i += 256) lhist[i] = 0;
  __syncthreads();
  int glo = lohi[0];                 // dense global base in ssrc
  int ne  = lohi[1];                 // <= SLOTS == SCAP
  int plo = b * SLOTS;               // bucket's fixed region in pairs
  for (int i = tid; i < ne; i += 256) {
    unsigned li = (unsigned)pairs[plo + i] & 255u;
    if (li < (unsigned)NPB) atomicAdd(&lhist[li], 1);
  }
  __syncthreads();
  int hv = (tid < NPB) ? lhist[tid] : 0;
  lscan[tid] = hv;
  __syncthreads();
  for (int off = 1; off < 256; off <<= 1) {
    int t = (tid >= off) ? lscan[tid - off] : 0;
    __syncthreads();
    lscan[tid] += t;
    __syncthreads();
  }
  if (tid < NPB) {
    int excl = lscan[tid] - hv;
    lcur[tid] = excl;
    unsigned sidx = (unsigned)(nbase + tid);
    if (sidx < (unsigned)N_NODES) start[sidx] = glo + excl;  // coalesced slice
  }
  __syncthreads();
  for (int i = tid; i < ne; i += 256) {
    int p = pairs[plo + i];
    unsigned li = (unsigned)p & 255u;
    if (li < (unsigned)NPB) {
      int pos = atomicAdd(&lcur[li], 1);
      if ((unsigned)pos < (unsigned)SCAP) obuf[pos] = (int)((unsigned)p >> 8);
    }
  }
  __syncthreads();
  for (int i = tid; i < ne; i += 256) {
    unsigned gi = (unsigned)(glo + i);
    if (gi < (unsigned)N_EDGES) ssrc[gi] = obuf[i];
  }
}

// ---------------------------------------------------------------------------
// K3 g1mlp (R19): 512 threads = 8 waves x 2 nodes each.  Halves the serial
// per-wave gather chain (R18 cycle model: per-block time ~= 4-node chain with
// near-zero inter-wave overlap -> more, shorter chains).  Gather body is the
// R15/R17-proven per-node loop, byte-identical math.  Barriers hoisted so all
// 512 threads reach them; MLP waves 0-3 layer-1, 0-2 layer-2.
// ---------------------------------------------------------------------------
__global__ __launch_bounds__(512) void g1mlp_kernel(
    const half8* __restrict__ xq,          // x rows [N][7] of half8 (112 B)
    const int* __restrict__ start, const int* __restrict__ ssrc,
    const unsigned* __restrict__ wt1l, const unsigned* __restrict__ wt1r,
    const unsigned* __restrict__ wt2l, const unsigned* __restrict__ wt2r,
    const float* __restrict__ b1, const float* __restrict__ b2,
    unsigned char* __restrict__ hlf8, _Float16* __restrict__ opart16,
    float one) {
  __shared__ float aggF[16][68];    // padded
  __shared__ float sH[16][68];      // h round-trip (padded)
  int tile = blockIdx.x;
  int wv = __builtin_amdgcn_readfirstlane(threadIdx.x >> 6);  // wave 0..7
  int lane = threadIdx.x & 63;
  int r = lane >> 3, q = lane & 7;
  bool qOK = (q < XQ);

  // ---- gather phase: wave wv owns nodes nb..nb+1 (2 nodes) ----
  int nb = tile * 16 + wv * 2;
  int st[3];
#pragma unroll
  for (int k = 0; k < 3; ++k) st[k] = clampoff(start[nb + k]);
  int iv[2];
#pragma unroll
  for (int k = 0; k < 2; ++k) {
    int cnt = st[k + 1] - st[k]; if (cnt > 64) cnt = 64;
    iv[k] = (lane < cnt) ? ssrc[st[k] + lane] : 0;
  }
#pragma unroll
  for (int k = 0; k < 2; ++k) {
    float accA[8] = {0.f, 0.f, 0.f, 0.f, 0.f, 0.f, 0.f, 0.f};
    float accB[8] = {0.f, 0.f, 0.f, 0.f, 0.f, 0.f, 0.f, 0.f};
    int s0 = st[k], s1 = st[k + 1];
    int idxv = iv[k];
    for (int base = s0; base < s1; base += 64) {
      int cnt = s1 - base;
      if (cnt > 64) cnt = 64;
      if (base != s0) idxv = (lane < cnt) ? ssrc[base + lane] : 0;
      int j = 0;
      for (; j + 16 <= cnt; j += 16) {
        int iA = clampidx(__shfl(idxv, j + r));
        int iB = clampidx(__shfl(idxv, j + 8 + r));
        if (qOK) {
          acc8(accA, xq[iA * XQ + q], one);
          acc8(accB, xq[iB * XQ + q], one);
        }
      }
      for (; j + 8 <= cnt; j += 8) {
        int iA = clampidx(__shfl(idxv, j + r));
        if (qOK) acc8(accA, xq[iA * XQ + q], one);
      }
      if (j < cnt) {
        int nrem = cnt - j;
        int iA = clampidx(__shfl(idxv, j + r));
        if (r < nrem && qOK) acc8(accA, xq[iA * XQ + q], one);
      }
    }
#pragma unroll
    for (int t = 0; t < 8; ++t) accA[t] += accB[t];
#pragma unroll
    for (int off = 8; off <= 32; off <<= 1) {
#pragma unroll
      for (int t = 0; t < 8; ++t) accA[t] += __shfl_xor(accA[t], off);
    }
    if (r == 0) {
      int nl = wv * 2 + k;
#pragma unroll
      for (int t = 0; t < 8; ++t) aggF[nl][q * 8 + t] = accA[t];  // q==7 -> 0s
    }
  }
  __syncthreads();

  // ---- MLP phase: waves 0-3 layer 1 ----
  int m = lane & 15, quad = lane >> 4;

  if (wv < 4) {
    half8 Aa[2], Ax[2];
#pragma unroll
    for (int s = 0; s < 2; ++s) {
      const float* pa = &aggF[m][s * 32 + quad * 8];
      half8 A;
#pragma unroll
      for (int jj = 0; jj < 8; ++jj) A[jj] = (_Float16)pa[jj];
      Aa[s] = A;
      int qq = s * 4 + quad;                         // feature quad 0..7
      half8 X = {0, 0, 0, 0, 0, 0, 0, 0};
      if (qq < XQ) X = xq[(tile * 16 + m) * XQ + qq];
      Ax[s] = X;
    }
    int n = wv * 16 + m;
    half8 Bl0 = *(const half8*)(wt1l + n * 32 + quad * 4);
    half8 Bl1 = *(const half8*)(wt1l + n * 32 + 16 + quad * 4);
    half8 Br0 = *(const half8*)(wt1r + n * 32 + quad * 4);
    half8 Br1 = *(const half8*)(wt1r + n * 32 + 16 + quad * 4);
    float4v acc1 = {0.f, 0.f, 0.f, 0.f};
    acc1 = __builtin_amdgcn_mfma_f32_16x16x32_f16(Aa[0], Bl0, acc1, 0, 0, 0);
    acc1 = __builtin_amdgcn_mfma_f32_16x16x32_f16(Aa[1], Bl1, acc1, 0, 0, 0);
    acc1 = __builtin_amdgcn_mfma_f32_16x16x32_f16(Ax[0], Br0, acc1, 0, 0, 0);
    acc1 = __builtin_amdgcn_mfma_f32_16x16x32_f16(Ax[1], Br1, acc1, 0, 0, 0);
    float bv = b1[n];
#pragma unroll
    for (int rr = 0; rr < 4; ++rr) {
      sH[quad * 4 + rr][n] = fmaxf(acc1[rr] + bv, 0.f);
    }
  }
  __syncthreads();

  // ---- layer 2: waves 0-2 ----
  if (wv >= 3) return;
  half8 Ah[2];
#pragma unroll
  for (int s = 0; s < 2; ++s) {
    const float* pr = &sH[m][s * 32 + quad * 8];
    half8 A;
#pragma unroll
    for (int jj = 0; jj < 8; ++jj) A[jj] = (_Float16)pr[jj];
    Ah[s] = A;
  }
  {
    int n = wv * 16 + m;
    half8 Cl0 = *(const half8*)(wt2l + n * 32 + quad * 4);
    half8 Cl1 = *(const half8*)(wt2l + n * 32 + 16 + quad * 4);
    half8 Cr0 = *(const half8*)(wt2r + n * 32 + quad * 4);
    half8 Cr1 = *(const half8*)(wt2r + n * 32 + 16 + quad * 4);
    float4v acc2 = {0.f, 0.f, 0.f, 0.f};
    float4v acc3 = {0.f, 0.f, 0.f, 0.f};
    acc2 = __builtin_amdgcn_mfma_f32_16x16x32_f16(Ah[0], Cl0, acc2, 0, 0, 0);
    acc2 = __builtin_amdgcn_mfma_f32_16x16x32_f16(Ah[1], Cl1, acc2, 0, 0, 0);
    acc3 = __builtin_amdgcn_mfma_f32_16x16x32_f16(Ah[0], Cr0, acc3, 0, 0, 0);
    acc3 = __builtin_amdgcn_mfma_f32_16x16x32_f16(Ah[1], Cr1, acc3, 0, 0, 0);
    float bv = (n < N_CLASSES) ? b2[n] : 0.f;
#pragma unroll
    for (int rr = 0; rr < 4; ++rr) {
      int row = tile * 16 + quad * 4 + rr;
      int v8 = __builtin_amdgcn_cvt_pk_fp8_f32(acc2[rr], acc2[rr], 0, 0);
      hlf8[row * NC48 + n] = (unsigned char)(v8 & 0xff);
      opart16[row * NC48 + n] = (_Float16)(acc3[rr] + bv);
    }
  }
}

// ---------------------------------------------------------------------------
// K4 g2tile (R19): 512 threads = 8 waves x 2 nodes; fp8 gather-2 + softmax.
// ---------------------------------------------------------------------------
#define AROW 49
__global__ __launch_bounds__(512) void g2tile_kernel(
    const uint2* __restrict__ hq,          // hlf8 rows [N][6] of uint2 (48 B)
    const _Float16* __restrict__ opart16,  // opart f16 [N][48]
    const int* __restrict__ start, const int* __restrict__ ssrc,
    float* __restrict__ out) {
  __shared__ float aggF[16][AROW];  // 16 agg rows (48 used), stride-49 padded
  int tile = blockIdx.x;
  int wv = __builtin_amdgcn_readfirstlane(threadIdx.x >> 6);  // wave 0..7
  int lane = threadIdx.x & 63;
  int r = lane >> 3, q = lane & 7;
  bool qOK = (q < 6);

  // ---- gather phase: wave wv owns nodes nb..nb+1 (2 nodes) ----
  int nb = tile * 16 + wv * 2;
  int st[3];
#pragma unroll
  for (int k = 0; k < 3; ++k) st[k] = clampoff(start[nb + k]);
  int iv[2];
#pragma unroll
  for (int k = 0; k < 2; ++k) {
    int cnt = st[k + 1] - st[k]; if (cnt > 64) cnt = 64;
    iv[k] = (lane < cnt) ? ssrc[st[k] + lane] : 0;
  }
#pragma unroll
  for (int k = 0; k < 2; ++k) {
    float accA[8] = {0.f, 0.f, 0.f, 0.f, 0.f, 0.f, 0.f, 0.f};
    float accB[8] = {0.f, 0.f, 0.f, 0.f, 0.f, 0.f, 0.f, 0.f};
    int s0 = st[k], s1 = st[k + 1];
    int idxv = iv[k];
    for (int base = s0; base < s1; base += 64) {
      int cnt = s1 - base;
      if (cnt > 64) cnt = 64;
      if (base != s0) idxv = (lane < cnt) ? ssrc[base + lane] : 0;
      int j = 0;
      for (; j + 16 <= cnt; j += 16) {
        int iA = clampidx(__shfl(idxv, j + r));
        int iB = clampidx(__shfl(idxv, j + 8 + r));
        if (qOK) {
          accf8(accA, hq[iA * 6 + q]);
          accf8(accB, hq[iB * 6 + q]);
        }
      }
      for (; j + 8 <= cnt; j += 8) {
        int iA = clampidx(__shfl(idxv, j + r));
        if (qOK) accf8(accA, hq[iA * 6 + q]);
      }
      if (j < cnt) {
        int nrem = cnt - j;
        int iA = clampidx(__shfl(idxv, j + r));
        if (r < nrem && qOK) accf8(accA, hq[iA * 6 + q]);
      }
    }
#pragma unroll
    for (int t = 0; t < 8; ++t) accA[t] += accB[t];
#pragma unroll
    for (int off = 8; off <= 32; off <<= 1) {
#pragma unroll
      for (int t = 0; t < 8; ++t) accA[t] += __shfl_xor(accA[t], off);
    }
    if (r == 0 && qOK) {
      int nl = wv * 2 + k;
#pragma unroll
      for (int t = 0; t < 8; ++t) aggF[nl][q * 8 + t] = accA[t];
    }
  }
  __syncthreads();

  // ---- softmax phase: wave 0 only (16 nodes x 4 class-slices) ----
  if (wv != 0) return;
  int m = lane >> 2, s = lane & 3;     // node-in-tile, class-slice
  int node = tile * 16 + m;

  float o[12];
#pragma unroll
  for (int j = 0; j < 12; ++j)
    o[j] = (float)opart16[node * NC48 + s * 12 + j];
  float lmax = -INFINITY;
#pragma unroll
  for (int j = 0; j < 12; ++j) {
    int f = s * 12 + j;
    o[j] += aggF[m][f];
    if (f < N_CLASSES) lmax = fmaxf(lmax, o[j]);
  }
  float vm = lmax;
#pragma unroll
  for (int off = 1; off <= 2; off <<= 1) vm = fmaxf(vm, __shfl_xor(vm, off));
  float lsum = 0.f;
#pragma unroll
  for (int j = 0; j < 12; ++j) {
    int f = s * 12 + j;
    if (f < N_CLASSES) lsum += expf(o[j] - vm);
  }
#pragma unroll
  for (int off = 1; off <= 2; off <<= 1) lsum += __shfl_xor(lsum, off);
  float lse = logf(lsum);
#pragma unroll
  for (int j = 0; j < 12; ++j) {
    int f = s * 12 + j;
    if (f < N_CLASSES) out[node * N_CLASSES + f] = o[j] - vm - lse;
  }
}

// ---------------------------------------------------------------------------
extern "C" void kernel_launch(void* const* d_in, const int* in_sizes, int n_in,
                              void* d_out, int out_size, void* d_ws, size_t ws_size,
                              hipStream_t stream) {
  const float* x   = (const float*)d_in[0];
  const float* W1l = (const float*)d_in[1];
  const float* W1r = (const float*)d_in[2];
  const float* b1  = (const float*)d_in[3];
  const float* W2l = (const float*)d_in[4];
  const float* W2r = (const float*)d_in[5];
  const float* b2  = (const float*)d_in[6];
  const int*   src = (const int*)d_in[7];
  const int*   dst = (const int*)d_in[8];
  float* out = (float*)d_out;

  // ---- byte-exact proven layout extents (ssrc at partial+64) ----
  int* counts  = (int*)d_ws;            // region hosts wcur2 only
  int* start   = counts + N_NODES;
  int* cursor  = start + (N_NODES + 1); // dead, reserved
  int* partial = cursor + N_NODES;      // dead, reserved
  int* ssrc    = partial + 64;
  unsigned* wt1l = (unsigned*)(ssrc + N_EDGES);
  unsigned* wt1r = wt1l + 2048;
  unsigned* wt2l = wt1r + 2048;
  unsigned* wt2r = wt2l + 1536;
  // 256-B align opart so all downstream quad accesses are naturally aligned
  uintptr_t pal = ((uintptr_t)(wt2r + 1536) + 255) & ~(uintptr_t)255;
  float* opart   = (float*)pal;
  _Float16* xh   = (_Float16*)(opart + (size_t)N_NODES * NC48);
  _Float16* hlh  = xh + (size_t)N_NODES * 64;

  // xq56 [N][56] f16 = 11.2 MB lives in xh's 12.8 MB slot.
  // hlf8 [N][48] fp8 = 4.8 MB lives in hlh's 9.6 MB slot.
  // opart16 [N][48] f16 = 9.6 MB lives in opart's 19.2 MB slot.
  _Float16* xq56    = xh;
  unsigned char* hlf8 = (unsigned char*)hlh;
  _Float16* opart16 = (_Float16*)opart;

  // wcur2[512] lives in the (otherwise dead) counts region.
  int* wcur2 = counts;

  // pairs: 500 x SLOTS ints = 8.2 MB, aliases the opart slot (19.2 MB):
  // fully consumed by sortprep before g1mlp writes opart16.
  int* pairs = (int*)opart;

  hipMemsetAsync(wcur2, 0, 512 * sizeof(int), stream);
  bucketA_kernel<<<BA_BLOCKS, 256, 0, stream>>>(src, dst, wcur2, pairs);
  sortprep_kernel<<<NBUK + PACKX_BLOCKS + PW_BLOCKS, 256, 0, stream>>>(
      pairs, wcur2, start, ssrc,
      x, xq56, W1l, W1r, W2l, W2r, wt1l, wt1r, wt2l, wt2r);

  g1mlp_kernel<<<N_TILES, 512, 0, stream>>>(
      (const half8*)xq56, start, ssrc, wt1l, wt1r, wt2l, wt2r,
      b1, b2, hlf8, opart16, 1.0f);

  g2tile_kernel<<<N_TILES, 512, 0, stream>>>(
      (const uint2*)hlf8, opart16, start, ssrc, out);
}

// Round 20
// 211.187 us; speedup vs baseline: 1.0485x; 1.0485x over previous
//
#include <hip/hip_runtime.h>
#include <hip/hip_bf16.h>
#include <math.h>

#define N_NODES   100000
#define N_EDGES   1600000
#define IN_FEAT   50
#define HIDDEN    64
#define N_CLASSES 41
#define NC48      48          // padded class width
#define N_TILES   (N_NODES / 16)   // 6250 exactly
#define XW        56          // packed x width (50 real + 6 pad), 112 B rows
#define XQ        7           // quads per x row

// bucketed counting sort (fixed-capacity regions, no pre-histogram)
#define NPB   200                      // nodes per bucket
#define NBUK  (N_NODES / NPB)          // 500 buckets exactly
#define SLOTS 4096                     // fixed region capacity per bucket
#define BEPT  16                       // edges per thread in bucketA
#define BA_BLOCKS ((N_EDGES + 256 * BEPT - 1) / (256 * BEPT))  // 391
#define SCAP  4096                     // sort2 LDS staging (== SLOTS)

#define PACKX_BLOCKS (N_NODES * XW / 256)   // 21875 exactly
#define PW_BLOCKS    28                     // 7168 / 256

typedef __attribute__((ext_vector_type(8))) _Float16 half8;
typedef __attribute__((ext_vector_type(4))) float   float4v;

union f16pk { _Float16 h[2]; unsigned u; };

// index clamp: any value outside [0,N_NODES) becomes 0 (defensive)
__device__ __forceinline__ int clampidx(int i) {
  return ((unsigned)i < (unsigned)N_NODES) ? i : 0;
}

// edge-offset clamp: any value outside [0,N_EDGES] becomes 0 (defensive)
__device__ __forceinline__ int clampoff(int v) {
  return ((unsigned)v <= (unsigned)N_EDGES) ? v : 0;
}

// f16 accumulate; `one` runtime arg prevents fma->fadd unfusing
__device__ __forceinline__ void acc8(float* acc, half8 u, float one) {
#pragma unroll
  for (int t = 0; t < 8; ++t) acc[t] = fmaf((float)u[t], one, acc[t]);
}

// fp8x8 (uint2) -> 8 f32 accumulate via HW v_cvt_pk_f32_fp8 (OCP e4m3)
__device__ __forceinline__ void accf8(float* acc, uint2 u) {
  auto p0 = __builtin_amdgcn_cvt_pk_f32_fp8(u.x, 0);
  auto p1 = __builtin_amdgcn_cvt_pk_f32_fp8(u.x, 1);
  auto p2 = __builtin_amdgcn_cvt_pk_f32_fp8(u.y, 0);
  auto p3 = __builtin_amdgcn_cvt_pk_f32_fp8(u.y, 1);
  acc[0] += p0[0]; acc[1] += p0[1];
  acc[2] += p1[0]; acc[3] += p1[1];
  acc[4] += p2[0]; acc[5] += p2[1];
  acc[6] += p3[0]; acc[7] += p3[1];
}

// ---------------------------------------------------------------------------
// K1 bucketA (R15-proven): fixed bucket regions, no pre-histogram.
// wcur2 zero-init via hipMemsetAsync (prep is OFF the critical path).
// lbase initialized for ALL buckets; region-relative both-sided write guard.
// ---------------------------------------------------------------------------
__global__ __launch_bounds__(256) void bucketA_kernel(
    const int* __restrict__ src, const int* __restrict__ dst,
    int* __restrict__ wcur2, int* __restrict__ pairs) {
  __shared__ int lcnt[NBUK];
  __shared__ int lbase[NBUK];
  int tid = threadIdx.x;
  for (int i = tid; i < NBUK; i += 256) { lcnt[i] = 0; lbase[i] = 0; }
  __syncthreads();

  int base = blockIdx.x * (256 * BEPT);
  int pk[BEPT], w[BEPT], rk[BEPT];
#pragma unroll
  for (int k = 0; k < BEPT; ++k) {
    int e = base + k * 256 + tid;
    rk[k] = -1;
    if (e < N_EDGES) {
      int sv = clampidx(src[e]);
      int d = clampidx(dst[e]);
      w[k] = (unsigned)d / (unsigned)NPB;           // < NBUK by construction
      pk[k] = (sv << 8) | (d - w[k] * NPB);
      rk[k] = atomicAdd(&lcnt[w[k]], 1);
    }
  }
  __syncthreads();
  for (int i = tid; i < NBUK; i += 256)
    if (lcnt[i]) lbase[i] = atomicAdd(&wcur2[i], lcnt[i]);
  __syncthreads();
#pragma unroll
  for (int k = 0; k < BEPT; ++k) {
    if (rk[k] >= 0) {
      unsigned rel = (unsigned)(lbase[w[k]] + rk[k]);
      if (rel < (unsigned)SLOTS) pairs[w[k] * SLOTS + (int)rel] = pk[k];
    }
  }
}

// ---------------------------------------------------------------------------
// K2 sortprep (R18-proven): MERGED dispatch.  Blocks 0..NBUK-1 run the
// per-bucket counting sort; blocks NBUK.. run prep (packx 56-wide f16 +
// packwts + start[] sentinel).  Data-independent halves fill the machine.
// ---------------------------------------------------------------------------
__global__ __launch_bounds__(256) void sortprep_kernel(
    const int* __restrict__ pairs, const int* __restrict__ wcur2,
    int* __restrict__ start, int* __restrict__ ssrc,
    const float* __restrict__ x, _Float16* __restrict__ xh,
    const float* __restrict__ W1l, const float* __restrict__ W1r,
    const float* __restrict__ W2l, const float* __restrict__ W2r,
    unsigned* __restrict__ wt1l, unsigned* __restrict__ wt1r,
    unsigned* __restrict__ wt2l, unsigned* __restrict__ wt2r) {
  __shared__ int obuf[SCAP];
  __shared__ int lhist[NPB];
  __shared__ int lcur[NPB];
  __shared__ int lscan[256];
  __shared__ int lohi[2];
  int tid = threadIdx.x;

  if (blockIdx.x >= NBUK) {
    // ---- prep half ----
    int bb = blockIdx.x - NBUK;
    if (bb < PACKX_BLOCKS) {
      int i = bb * 256 + tid;                        // < N*56 exactly
      int node = i / XW, c = i - node * XW;
      xh[i] = (c < IN_FEAT) ? (_Float16)x[node * IN_FEAT + c] : (_Float16)0.f;
      return;
    }
    if (bb == PACKX_BLOCKS && tid == 0) start[N_NODES] = N_EDGES;  // sentinel
    int i = (bb - PACKX_BLOCKS) * 256 + tid;         // [0, 7168)
    f16pk pk;
    if (i < 2048 * 2) {                       // layer-1 weights
      int which = i >> 11, j = i & 2047;
      int n = j >> 5, kp = j & 31;
      const float* W = which ? W1r : W1l;
      int k0 = 2 * kp, k1 = 2 * kp + 1;
      pk.h[0] = (_Float16)((k0 < IN_FEAT) ? W[k0 * HIDDEN + n] : 0.f);
      pk.h[1] = (_Float16)((k1 < IN_FEAT) ? W[k1 * HIDDEN + n] : 0.f);
      (which ? wt1r : wt1l)[j] = pk.u;
    } else if (i < 4096 + 2 * 1536) {         // layer-2 weights
      int j = i - 4096;
      int which = (j >= 1536), jj = which ? j - 1536 : j;
      int n = jj >> 5, kp = jj & 31;
      const float* W = which ? W2r : W2l;
      pk.h[0] = (_Float16)((n < N_CLASSES) ? W[(2 * kp) * N_CLASSES + n] : 0.f);
      pk.h[1] = (_Float16)((n < N_CLASSES) ? W[(2 * kp + 1) * N_CLASSES + n] : 0.f);
      (which ? wt2r : wt2l)[jj] = pk.u;
    }
    return;
  }

  // ---- sort2 half (R15-proven body) ----
  int b = blockIdx.x;
  int nbase = b * NPB;
  {
    int i0 = 2 * tid, i1 = 2 * tid + 1;
    int a0 = (i0 < NBUK) ? min(max(wcur2[i0], 0), SLOTS) : 0;
    int a1 = (i1 < NBUK) ? min(max(wcur2[i1], 0), SLOTS) : 0;
    int s = a0 + a1;
    lscan[tid] = s;
    __syncthreads();
    for (int off = 1; off < 256; off <<= 1) {
      int t = (tid >= off) ? lscan[tid - off] : 0;
      __syncthreads();
      lscan[tid] += t;
      __syncthreads();
    }
    int excl = lscan[tid] - s;
    if (i0 == b) { lohi[0] = excl;      lohi[1] = a0; }
    if (i1 == b) { lohi[0] = excl + a0; lohi[1] = a1; }
  }
  for (int i = tid; i < NPB; i += 256) lhist[i] = 0;
  __syncthreads();
  int glo = lohi[0];                 // dense global base in ssrc
  int ne  = lohi[1];                 // <= SLOTS == SCAP
  int plo = b * SLOTS;               // bucket's fixed region in pairs
  for (int i = tid; i < ne; i += 256) {
    unsigned li = (unsigned)pairs[plo + i] & 255u;
    if (li < (unsigned)NPB) atomicAdd(&lhist[li], 1);
  }
  __syncthreads();
  int hv = (tid < NPB) ? lhist[tid] : 0;
  lscan[tid] = hv;
  __syncthreads();
  for (int off = 1; off < 256; off <<= 1) {
    int t = (tid >= off) ? lscan[tid - off] : 0;
    __syncthreads();
    lscan[tid] += t;
    __syncthreads();
  }
  if (tid < NPB) {
    int excl = lscan[tid] - hv;
    lcur[tid] = excl;
    unsigned sidx = (unsigned)(nbase + tid);
    if (sidx < (unsigned)N_NODES) start[sidx] = glo + excl;  // coalesced slice
  }
  __syncthreads();
  for (int i = tid; i < ne; i += 256) {
    int p = pairs[plo + i];
    unsigned li = (unsigned)p & 255u;
    if (li < (unsigned)NPB) {
      int pos = atomicAdd(&lcur[li], 1);
      if ((unsigned)pos < (unsigned)SCAP) obuf[pos] = (int)((unsigned)p >> 8);
    }
  }
  __syncthreads();
  for (int i = tid; i < ne; i += 256) {
    unsigned gi = (unsigned)(glo + i);
    if (gi < (unsigned)N_EDGES) ssrc[gi] = obuf[i];
  }
}

// ---------------------------------------------------------------------------
// K3 g1mlp (R17/R18-proven): 256 threads, 4 waves x 4 nodes; pipelined
// gather over 56-wide xq; wave-parallel MFMA MLP; fp8 hl + f16 opart.
// ---------------------------------------------------------------------------
__global__ __launch_bounds__(256) void g1mlp_kernel(
    const half8* __restrict__ xq,          // x rows [N][7] of half8 (112 B)
    const int* __restrict__ start, const int* __restrict__ ssrc,
    const unsigned* __restrict__ wt1l, const unsigned* __restrict__ wt1r,
    const unsigned* __restrict__ wt2l, const unsigned* __restrict__ wt2r,
    const float* __restrict__ b1, const float* __restrict__ b2,
    unsigned char* __restrict__ hlf8, _Float16* __restrict__ opart16,
    float one) {
  __shared__ float aggF[16][68];    // padded
  __shared__ float sH[16][68];      // h round-trip (padded)
  int tile = blockIdx.x;
  int wv = __builtin_amdgcn_readfirstlane(threadIdx.x >> 6);  // wave 0..3
  int lane = threadIdx.x & 63;
  int r = lane >> 3, q = lane & 7;
  bool qOK = (q < XQ);

  // ---- gather phase (pipelined, R15 structure): nodes nb..nb+3 ----
  int nb = tile * 16 + wv * 4;
  int st[5];
#pragma unroll
  for (int k = 0; k < 5; ++k) st[k] = clampoff(start[nb + k]);
  int iv[4];
#pragma unroll
  for (int k = 0; k < 4; ++k) {
    int cnt = st[k + 1] - st[k]; if (cnt > 64) cnt = 64;
    iv[k] = (lane < cnt) ? ssrc[st[k] + lane] : 0;
  }
#pragma unroll
  for (int k = 0; k < 4; ++k) {
    float accA[8] = {0.f, 0.f, 0.f, 0.f, 0.f, 0.f, 0.f, 0.f};
    float accB[8] = {0.f, 0.f, 0.f, 0.f, 0.f, 0.f, 0.f, 0.f};
    int s0 = st[k], s1 = st[k + 1];
    int idxv = iv[k];
    for (int base = s0; base < s1; base += 64) {
      int cnt = s1 - base;
      if (cnt > 64) cnt = 64;
      if (base != s0) idxv = (lane < cnt) ? ssrc[base + lane] : 0;
      int j = 0;
      for (; j + 16 <= cnt; j += 16) {
        int iA = clampidx(__shfl(idxv, j + r));
        int iB = clampidx(__shfl(idxv, j + 8 + r));
        if (qOK) {
          acc8(accA, xq[iA * XQ + q], one);
          acc8(accB, xq[iB * XQ + q], one);
        }
      }
      for (; j + 8 <= cnt; j += 8) {
        int iA = clampidx(__shfl(idxv, j + r));
        if (qOK) acc8(accA, xq[iA * XQ + q], one);
      }
      if (j < cnt) {
        int nrem = cnt - j;
        int iA = clampidx(__shfl(idxv, j + r));
        if (r < nrem && qOK) acc8(accA, xq[iA * XQ + q], one);
      }
    }
#pragma unroll
    for (int t = 0; t < 8; ++t) accA[t] += accB[t];
#pragma unroll
    for (int off = 8; off <= 32; off <<= 1) {
#pragma unroll
      for (int t = 0; t < 8; ++t) accA[t] += __shfl_xor(accA[t], off);
    }
    if (r == 0) {
      int nl = wv * 4 + k;
#pragma unroll
      for (int t = 0; t < 8; ++t) aggF[nl][q * 8 + t] = accA[t];  // q==7 -> 0s
    }
  }
  __syncthreads();

  // ---- MLP phase: all 4 waves ----
  int m = lane & 15, quad = lane >> 4;

  half8 Aa[2], Ax[2];
#pragma unroll
  for (int s = 0; s < 2; ++s) {
    const float* pa = &aggF[m][s * 32 + quad * 8];
    half8 A;
#pragma unroll
    for (int jj = 0; jj < 8; ++jj) A[jj] = (_Float16)pa[jj];
    Aa[s] = A;
    int qq = s * 4 + quad;                           // feature quad 0..7
    half8 X = {0, 0, 0, 0, 0, 0, 0, 0};
    if (qq < XQ) X = xq[(tile * 16 + m) * XQ + qq];
    Ax[s] = X;
  }

  // layer 1: wave wv computes n-tile wv (n = wv*16 + m)
  {
    int n = wv * 16 + m;
    half8 Bl0 = *(const half8*)(wt1l + n * 32 + quad * 4);
    half8 Bl1 = *(const half8*)(wt1l + n * 32 + 16 + quad * 4);
    half8 Br0 = *(const half8*)(wt1r + n * 32 + quad * 4);
    half8 Br1 = *(const half8*)(wt1r + n * 32 + 16 + quad * 4);
    float4v acc1 = {0.f, 0.f, 0.f, 0.f};
    acc1 = __builtin_amdgcn_mfma_f32_16x16x32_f16(Aa[0], Bl0, acc1, 0, 0, 0);
    acc1 = __builtin_amdgcn_mfma_f32_16x16x32_f16(Aa[1], Bl1, acc1, 0, 0, 0);
    acc1 = __builtin_amdgcn_mfma_f32_16x16x32_f16(Ax[0], Br0, acc1, 0, 0, 0);
    acc1 = __builtin_amdgcn_mfma_f32_16x16x32_f16(Ax[1], Br1, acc1, 0, 0, 0);
    float bv = b1[n];
#pragma unroll
    for (int rr = 0; rr < 4; ++rr) {
      sH[quad * 4 + rr][n] = fmaxf(acc1[rr] + bv, 0.f);
    }
  }
  __syncthreads();

  // layer 2: waves 0..2 compute n-tile wv
  if (wv >= 3) return;
  half8 Ah[2];
#pragma unroll
  for (int s = 0; s < 2; ++s) {
    const float* pr = &sH[m][s * 32 + quad * 8];
    half8 A;
#pragma unroll
    for (int jj = 0; jj < 8; ++jj) A[jj] = (_Float16)pr[jj];
    Ah[s] = A;
  }
  {
    int n = wv * 16 + m;
    half8 Cl0 = *(const half8*)(wt2l + n * 32 + quad * 4);
    half8 Cl1 = *(const half8*)(wt2l + n * 32 + 16 + quad * 4);
    half8 Cr0 = *(const half8*)(wt2r + n * 32 + quad * 4);
    half8 Cr1 = *(const half8*)(wt2r + n * 32 + 16 + quad * 4);
    float4v acc2 = {0.f, 0.f, 0.f, 0.f};
    float4v acc3 = {0.f, 0.f, 0.f, 0.f};
    acc2 = __builtin_amdgcn_mfma_f32_16x16x32_f16(Ah[0], Cl0, acc2, 0, 0, 0);
    acc2 = __builtin_amdgcn_mfma_f32_16x16x32_f16(Ah[1], Cl1, acc2, 0, 0, 0);
    acc3 = __builtin_amdgcn_mfma_f32_16x16x32_f16(Ah[0], Cr0, acc3, 0, 0, 0);
    acc3 = __builtin_amdgcn_mfma_f32_16x16x32_f16(Ah[1], Cr1, acc3, 0, 0, 0);
    float bv = (n < N_CLASSES) ? b2[n] : 0.f;
#pragma unroll
    for (int rr = 0; rr < 4; ++rr) {
      int row = tile * 16 + quad * 4 + rr;
      int v8 = __builtin_amdgcn_cvt_pk_fp8_f32(acc2[rr], acc2[rr], 0, 0);
      hlf8[row * NC48 + n] = (unsigned char)(v8 & 0xff);
      opart16[row * NC48 + n] = (_Float16)(acc3[rr] + bv);
    }
  }
}

// ---------------------------------------------------------------------------
// K4 g2tile (R17/R18-proven): 256 threads, pipelined fp8 gather-2 + batched
// softmax; opart read as f16.
// ---------------------------------------------------------------------------
#define AROW 49
__global__ __launch_bounds__(256) void g2tile_kernel(
    const uint2* __restrict__ hq,          // hlf8 rows [N][6] of uint2 (48 B)
    const _Float16* __restrict__ opart16,  // opart f16 [N][48]
    const int* __restrict__ start, const int* __restrict__ ssrc,
    float* __restrict__ out) {
  __shared__ float aggF[16][AROW];  // 16 agg rows (48 used), stride-49 padded
  int tile = blockIdx.x;
  int wv = __builtin_amdgcn_readfirstlane(threadIdx.x >> 6);  // wave 0..3
  int lane = threadIdx.x & 63;
  int r = lane >> 3, q = lane & 7;
  bool qOK = (q < 6);

  // ---- gather phase (pipelined, R15 structure): nodes nb..nb+3 ----
  int nb = tile * 16 + wv * 4;
  int st[5];
#pragma unroll
  for (int k = 0; k < 5; ++k) st[k] = clampoff(start[nb + k]);
  int iv[4];
#pragma unroll
  for (int k = 0; k < 4; ++k) {
    int cnt = st[k + 1] - st[k]; if (cnt > 64) cnt = 64;
    iv[k] = (lane < cnt) ? ssrc[st[k] + lane] : 0;
  }
#pragma unroll
  for (int k = 0; k < 4; ++k) {
    float accA[8] = {0.f, 0.f, 0.f, 0.f, 0.f, 0.f, 0.f, 0.f};
    float accB[8] = {0.f, 0.f, 0.f, 0.f, 0.f, 0.f, 0.f, 0.f};
    int s0 = st[k], s1 = st[k + 1];
    int idxv = iv[k];
    for (int base = s0; base < s1; base += 64) {
      int cnt = s1 - base;
      if (cnt > 64) cnt = 64;
      if (base != s0) idxv = (lane < cnt) ? ssrc[base + lane] : 0;
      int j = 0;
      for (; j + 16 <= cnt; j += 16) {
        int iA = clampidx(__shfl(idxv, j + r));
        int iB = clampidx(__shfl(idxv, j + 8 + r));
        if (qOK) {
          accf8(accA, hq[iA * 6 + q]);
          accf8(accB, hq[iB * 6 + q]);
        }
      }
      for (; j + 8 <= cnt; j += 8) {
        int iA = clampidx(__shfl(idxv, j + r));
        if (qOK) accf8(accA, hq[iA * 6 + q]);
      }
      if (j < cnt) {
        int nrem = cnt - j;
        int iA = clampidx(__shfl(idxv, j + r));
        if (r < nrem && qOK) accf8(accA, hq[iA * 6 + q]);
      }
    }
#pragma unroll
    for (int t = 0; t < 8; ++t) accA[t] += accB[t];
#pragma unroll
    for (int off = 8; off <= 32; off <<= 1) {
#pragma unroll
      for (int t = 0; t < 8; ++t) accA[t] += __shfl_xor(accA[t], off);
    }
    if (r == 0 && qOK) {
      int nl = wv * 4 + k;
#pragma unroll
      for (int t = 0; t < 8; ++t) aggF[nl][q * 8 + t] = accA[t];
    }
  }
  __syncthreads();

  // ---- softmax phase: wave 0 only (16 nodes x 4 class-slices) ----
  if (wv != 0) return;
  int m = lane >> 2, s = lane & 3;     // node-in-tile, class-slice
  int node = tile * 16 + m;

  float o[12];
#pragma unroll
  for (int j = 0; j < 12; ++j)
    o[j] = (float)opart16[node * NC48 + s * 12 + j];
  float lmax = -INFINITY;
#pragma unroll
  for (int j = 0; j < 12; ++j) {
    int f = s * 12 + j;
    o[j] += aggF[m][f];
    if (f < N_CLASSES) lmax = fmaxf(lmax, o[j]);
  }
  float vm = lmax;
#pragma unroll
  for (int off = 1; off <= 2; off <<= 1) vm = fmaxf(vm, __shfl_xor(vm, off));
  float lsum = 0.f;
#pragma unroll
  for (int j = 0; j < 12; ++j) {
    int f = s * 12 + j;
    if (f < N_CLASSES) lsum += expf(o[j] - vm);
  }
#pragma unroll
  for (int off = 1; off <= 2; off <<= 1) lsum += __shfl_xor(lsum, off);
  float lse = logf(lsum);
#pragma unroll
  for (int j = 0; j < 12; ++j) {
    int f = s * 12 + j;
    if (f < N_CLASSES) out[node * N_CLASSES + f] = o[j] - vm - lse;
  }
}

// ---------------------------------------------------------------------------
extern "C" void kernel_launch(void* const* d_in, const int* in_sizes, int n_in,
                              void* d_out, int out_size, void* d_ws, size_t ws_size,
                              hipStream_t stream) {
  const float* x   = (const float*)d_in[0];
  const float* W1l = (const float*)d_in[1];
  const float* W1r = (const float*)d_in[2];
  const float* b1  = (const float*)d_in[3];
  const float* W2l = (const float*)d_in[4];
  const float* W2r = (const float*)d_in[5];
  const float* b2  = (const float*)d_in[6];
  const int*   src = (const int*)d_in[7];
  const int*   dst = (const int*)d_in[8];
  float* out = (float*)d_out;

  // ---- byte-exact proven layout extents (ssrc at partial+64) ----
  int* counts  = (int*)d_ws;            // region hosts wcur2 only
  int* start   = counts + N_NODES;
  int* cursor  = start + (N_NODES + 1); // dead, reserved
  int* partial = cursor + N_NODES;      // dead, reserved
  int* ssrc    = partial + 64;
  unsigned* wt1l = (unsigned*)(ssrc + N_EDGES);
  unsigned* wt1r = wt1l + 2048;
  unsigned* wt2l = wt1r + 2048;
  unsigned* wt2r = wt2l + 1536;
  // 256-B align opart so all downstream quad accesses are naturally aligned
  uintptr_t pal = ((uintptr_t)(wt2r + 1536) + 255) & ~(uintptr_t)255;
  float* opart   = (float*)pal;
  _Float16* xh   = (_Float16*)(opart + (size_t)N_NODES * NC48);
  _Float16* hlh  = xh + (size_t)N_NODES * 64;

  // xq56 [N][56] f16 = 11.2 MB lives in xh's 12.8 MB slot.
  // hlf8 [N][48] fp8 = 4.8 MB lives in hlh's 9.6 MB slot.
  // opart16 [N][48] f16 = 9.6 MB lives in opart's 19.2 MB slot.
  _Float16* xq56    = xh;
  unsigned char* hlf8 = (unsigned char*)hlh;
  _Float16* opart16 = (_Float16*)opart;

  // wcur2[512] lives in the (otherwise dead) counts region.
  int* wcur2 = counts;

  // pairs: 500 x SLOTS ints = 8.2 MB, aliases the opart slot (19.2 MB):
  // fully consumed by sortprep before g1mlp writes opart16.
  int* pairs = (int*)opart;

  hipMemsetAsync(wcur2, 0, 512 * sizeof(int), stream);
  bucketA_kernel<<<BA_BLOCKS, 256, 0, stream>>>(src, dst, wcur2, pairs);
  sortprep_kernel<<<NBUK + PACKX_BLOCKS + PW_BLOCKS, 256, 0, stream>>>(
      pairs, wcur2, start, ssrc,
      x, xq56, W1l, W1r, W2l, W2r, wt1l, wt1r, wt2l, wt2r);

  g1mlp_kernel<<<N_TILES, 256, 0, stream>>>(
      (const half8*)xq56, start, ssrc, wt1l, wt1r, wt2l, wt2r,
      b1, b2, hlf8, opart16, 1.0f);

  g2tile_kernel<<<N_TILES, 256, 0, stream>>>(
      (const uint2*)hlf8, opart16, start, ssrc, out);
}